// Round 1
// baseline (23925.964 us; speedup 1.0000x reference)
//
#include <hip/hip_runtime.h>
#include <cstdint>
#include <cstddef>

#define V_  50257
#define H_  256
#define E_  64
#define T_  2048
#define G4_ 1024
#define OSTRIDE 50348
#define CMROWS 820
#define PSTR 832          // PRE row stride: 832*4B = 26 cache lines -> per-t regions line-disjoint
#define NGRP 16           // PRE row groups
#define RPB 52            // rows per group (16*52 = 832 >= 820)
#define NPREB 32          // PRE worker blocks: 16 groups x 2 time parities
#define WSTR 257          // LDS stride for worker weight rows (spreads banks: (lr*257+k)%32=(lr+k)%32)

typedef __attribute__((ext_vector_type(2))) _Float16 half2v;
typedef __attribute__((ext_vector_type(8))) short short8v;
typedef __attribute__((ext_vector_type(4))) float floatx4;

__device__ __forceinline__ float fdot2u(unsigned a, unsigned b, float acc){
  return __builtin_amdgcn_fdot2(__builtin_bit_cast(half2v, a),
                                __builtin_bit_cast(half2v, b), acc, false);
}
__device__ __forceinline__ unsigned packh2(float a, float b){
  half2v h; h.x = (_Float16)a; h.y = (_Float16)b;
  return __builtin_bit_cast(unsigned, h);
}
__device__ __forceinline__ unsigned short f2bf(float f){
  unsigned u = __builtin_bit_cast(unsigned, f);
  u += 0x7fffu + ((u >> 16) & 1u);
  return (unsigned short)(u >> 16);
}
__device__ __forceinline__ float sigm(float x){
  return __builtin_amdgcn_rcpf(1.0f + __expf(-x));
}
__device__ __forceinline__ float tanh_f(float x){
  float e = __expf(2.0f * x);
  return (e - 1.0f) * __builtin_amdgcn_rcpf(e + 1.0f);
}
__device__ __forceinline__ float dot4(uint4 w, uint4 h, float acc){
  acc = fdot2u(w.x, h.x, acc); acc = fdot2u(w.y, h.y, acc);
  acc = fdot2u(w.z, h.z, acc); acc = fdot2u(w.w, h.w, acc);
  return acc;
}

// agent-scope sync helpers (cross-XCD correctness per Guideline 16)
__device__ __forceinline__ int ld_acq(int* p){
  return __hip_atomic_load(p, __ATOMIC_ACQUIRE, __HIP_MEMORY_SCOPE_AGENT);
}
__device__ __forceinline__ int ld_rlx(int* p){
  return __hip_atomic_load(p, __ATOMIC_RELAXED, __HIP_MEMORY_SCOPE_AGENT);
}
__device__ __forceinline__ void st_rel(int* p, int v){
  __hip_atomic_store(p, v, __ATOMIC_RELEASE, __HIP_MEMORY_SCOPE_AGENT);
}

// ---------------------------------------------------------------------------
// k_prep: out_W -> bf16 (OWB), W_ih -> transposed WT [k][r], W_hh -> f16 pack WP
// ---------------------------------------------------------------------------
__global__ void k_prep(const float* __restrict__ out_W, const float* __restrict__ W_ih,
                       const float* __restrict__ W_hh,
                       unsigned short* __restrict__ OWB, float* __restrict__ WT,
                       unsigned* __restrict__ WP){
  const long n0 = (long)V_ * H_;
  const long n1 = (long)G4_ * H_;
  const long n2 = 32l * G4_;
  const long total = n0 + n1 + n2;
  for (long id = (long)blockIdx.x * blockDim.x + threadIdx.x; id < total;
       id += (long)gridDim.x * blockDim.x){
    if (id < n0){
      OWB[id] = f2bf(out_W[id]);
    } else if (id < n0 + n1){
      long i = id - n0;                 // i = k*1024 + r
      int r = (int)(i & 1023), k = (int)(i >> 10);
      WT[i] = W_ih[r * H_ + k];
    } else {
      long i = id - n0 - n1;
      int t = (int)(i & 1023), j4 = (int)(i >> 10);
      int r0 = t >> 2, s = t & 3;
      #pragma unroll
      for (int d = 0; d < 4; ++d){
        int j = j4 * 4 + d;
        int ri = j >> 5, c = j & 31;
        int grow = ri * H_ + r0;
        int k0 = s * 64 + c * 2;
        WP[(j4 * 1024 + t) * 4 + d] = packh2(W_hh[grow * H_ + k0],
                                             W_hh[grow * H_ + k0 + 1]);
      }
    }
  }
}

// ---------------------------------------------------------------------------
// k_cm: build CMR [820][256] row-major combined matrix (same values as before,
// row-major so the pipelined PRE workers can stage their rows coalesced).
// ---------------------------------------------------------------------------
__global__ void k_cm(const float* __restrict__ Wdelta, const float* __restrict__ Went,
                     const float* __restrict__ We, const float* __restrict__ r_emb,
                     const float* __restrict__ Wr, const float* __restrict__ Wlen,
                     float* __restrict__ CMR){
  const int total = CMROWS * H_;
  for (int id = blockIdx.x * blockDim.x + threadIdx.x; id < total;
       id += gridDim.x * blockDim.x){
    int r = id >> 8, k = id & 255;
    float v;
    if (r < 256)      v = Wdelta[r * H_ + k];
    else if (r < 512) v = Went[k * H_ + (r - 256)];
    else if (r < 768) v = We[(r - 512) * H_ + k];
    else if (r < 770){
      int i = r - 768; float acc = 0.f;
      for (int m = 0; m < H_; ++m) acc += r_emb[i * H_ + m] * Wr[m * H_ + k];
      v = acc;
    }
    else if (r < 795) v = Wlen[(r - 770) * 2 * H_ + k];
    else              v = Wlen[(r - 795) * 2 * H_ + H_ + k];
    CMR[r * H_ + k] = v;
  }
}

// ---------------------------------------------------------------------------
// k_init: G_init = E0@Went, M_init = E0@We^T, L_init = E0@WlenE^T, ENTS = E0
// ---------------------------------------------------------------------------
__global__ void k_init(const float* __restrict__ E0, const float* __restrict__ Went,
                       const float* __restrict__ We, const float* __restrict__ Wlen,
                       float* __restrict__ GI, float* __restrict__ MST,
                       float* __restrict__ LST, float* __restrict__ ENTS){
  const int nG = E_ * H_, nM = E_ * H_, nL = E_ * 32, nC = E_ * H_;
  const int total = nG + nM + nL + nC;
  for (int id = blockIdx.x * blockDim.x + threadIdx.x; id < total;
       id += gridDim.x * blockDim.x){
    if (id < nG){
      int j = id >> 8, i = id & 255; float a = 0.f;
      for (int k = 0; k < H_; ++k) a += E0[j * H_ + k] * Went[k * H_ + i];
      GI[id] = a;
    } else if (id < nG + nM){
      int x = id - nG; int j = x >> 8, i = x & 255; float a = 0.f;
      for (int k = 0; k < H_; ++k) a += E0[j * H_ + k] * We[i * H_ + k];
      MST[x] = a;
    } else if (id < nG + nM + nL){
      int x = id - nG - nM; int j = x >> 5, i = x & 31; float a = 0.f;
      if (i < 25)
        for (int k = 0; k < H_; ++k) a += E0[j * H_ + k] * Wlen[i * 2 * H_ + H_ + k];
      LST[x] = a;
    } else {
      int x = id - nG - nM - nL;
      ENTS[x] = E0[x];
    }
  }
}

// ---------------------------------------------------------------------------
// k_a: A4[t][r0][gate] = W_ih@emb[tok_t] + b_ih + b_hh  (8 timesteps / block)
// ---------------------------------------------------------------------------
__global__ __launch_bounds__(1024) void k_a(const int* __restrict__ tokens,
                                            const float* __restrict__ emb,
                                            const float* __restrict__ WT,
                                            const float* __restrict__ b_ih,
                                            const float* __restrict__ b_hh,
                                            float* __restrict__ A4){
  __shared__ __align__(16) float xs[H_][8];
  const int t0 = blockIdx.x * 8;
  const int tid = threadIdx.x;
  for (int id = tid; id < 8 * H_; id += 1024){
    int k = id >> 3, tl = id & 7;
    xs[k][tl] = emb[(size_t)tokens[t0 + tl] * H_ + k];
  }
  __syncthreads();
  const int r = tid;
  const float base = b_ih[r] + b_hh[r];
  float acc[8];
  #pragma unroll
  for (int i = 0; i < 8; ++i) acc[i] = base;
  for (int k = 0; k < H_; ++k){
    float w = WT[k * G4_ + r];
    floatx4 x0 = *(const floatx4*)&xs[k][0];
    floatx4 x1 = *(const floatx4*)&xs[k][4];
    acc[0] += w * x0.x; acc[1] += w * x0.y; acc[2] += w * x0.z; acc[3] += w * x0.w;
    acc[4] += w * x1.x; acc[5] += w * x1.y; acc[6] += w * x1.z; acc[7] += w * x1.w;
  }
  const int r0 = r & 255, g = r >> 8;
  #pragma unroll
  for (int tl = 0; tl < 8; ++tl)
    A4[(((t0 + tl) * H_ + r0) << 2) + g] = acc[tl];
}

// ---------------------------------------------------------------------------
// k_pipe: fused producer/consumer pipeline over t.
//   block 0        : LSTM (512 active threads), publishes prog_h per step
//   blocks 1..32   : PRE workers: group g = (b-1)&15 owns rows [52g,52g+52),
//                    parity p = (b-1)>>4 handles t = p, p+2, ...
//                    math is the exact sequential fma chain of the old k_pre.
//   block 33       : ENT scan (1024 threads), identical math to old k_ent,
//                    gated per-step on pre_done[t+1]==16 (relaxed pre-sample,
//                    acquire only in the rare spin path).
// All 34 blocks co-resident (<< 256 CUs) => no deadlock possible.
// ---------------------------------------------------------------------------
struct LstmS { unsigned hsh[4 * 36]; uint4 olds[7 * 512]; };           // 57920 B
struct PreS  { float wrow[RPB * WSTR]; float hbuf[H_]; };              // 54480 B
struct EntS  {
  unsigned Gsh[E_ * 132];
  unsigned hsh2[2][128];
  float Hld[2][H_], Dld[2][H_], Wld[2][H_], Vld[2][H_];
  float EXs[2][64];
  float Ssh[E_], DSH[E_];
  float red[8][2];
  float sc[4];
};                                                                     // 44112 B
union PipeS { LstmS l; PreS p; EntS e; };

__global__ __launch_bounds__(1024, 1) void k_pipe(
    const uint4* __restrict__ WP4, const floatx4* __restrict__ A4,
    float* Hws, const float* __restrict__ CMR, float* PRE,
    const int* __restrict__ ids, const float* __restrict__ GI,
    const float* __restrict__ dist_init, const float* __restrict__ We_b,
    const float* __restrict__ Wlen_b, const float* __restrict__ wdW,
    const float* __restrict__ wdB, const float* __restrict__ WdeltaB,
    const float* __restrict__ WentB, const float* __restrict__ WrB,
    float* __restrict__ ENTS, float* __restrict__ MST, float* __restrict__ LST,
    unsigned short* __restrict__ Zb, float* __restrict__ out,
    int* prog_h, int* pre_done)
{
  __shared__ PipeS sm;
  const int tid = threadIdx.x;
  const int bid = blockIdx.x;

  if (bid == 0){
    // ------------------------- LSTM producer -------------------------
    unsigned* hsh = sm.l.hsh;
    uint4* olds = sm.l.olds;
    const int r0 = tid >> 1, s2 = tid & 1;
    const int tA = r0 * 4 + 2 * s2;
    const int tB = tA + 1;
    const int sA = 2 * s2;
    const bool act = (tid < 512);

    uint4 wA[32], wB[16];
    if (act){
      #pragma unroll
      for (int j4 = 0; j4 < 32; ++j4) wA[j4] = WP4[j4 * 1024 + tA];
      #pragma unroll
      for (int j4 = 0; j4 < 16; ++j4) wB[j4] = WP4[j4 * 1024 + tB];
      #pragma unroll
      for (int j4 = 24; j4 < 31; ++j4) olds[(j4 - 24) * 512 + tid] = WP4[j4 * 1024 + tB];
    }
    if (tid < 144) hsh[tid] = 0u;

    const uint4* gsrc = act ? &WP4[16 * 1024 + tB] : WP4;
    uint4 g_cur = {0u, 0u, 0u, 0u};
    if (act) g_cur = gsrc[0];
    float c = 0.0f;
    floatx4 a_cur = (floatx4){0.f, 0.f, 0.f, 0.f};
    if (act) a_cur = A4[r0];
    floatx4 a_nxt = a_cur;
    __syncthreads();

    for (int t = 0; t < T_; ++t){
      float hn = 0.f;
      if (act){
        if (t + 1 < T_) a_nxt = A4[(t + 1) * H_ + r0];
        uint4 o_strm = gsrc[15 * 1024];
        float acc0 = a_cur.x * 0.5f, acc1 = a_cur.y * 0.5f;
        float acc2 = a_cur.z * 0.5f, acc3 = a_cur.w * 0.5f;
        #pragma unroll
        for (int cc = 0; cc < 8; ++cc){
          uint4 g_nxt = gsrc[((cc < 7) ? (cc + 1) : 0) * 1024];
          uint4 hA = *(const uint4*)&hsh[sA * 36 + cc * 4];
          uint4 hB = *(const uint4*)&hsh[sA * 36 + 36 + cc * 4];
          acc0 = dot4(wA[cc],      hA, acc0);
          acc1 = dot4(wA[8 + cc],  hA, acc1);
          acc2 = dot4(wA[16 + cc], hA, acc2);
          acc3 = dot4(wA[24 + cc], hA, acc3);
          acc0 = dot4(wB[cc],      hB, acc0);
          acc1 = dot4(wB[8 + cc],  hB, acc1);
          acc2 = dot4(g_cur,       hB, acc2);
          uint4 xo = (cc < 7) ? olds[cc * 512 + tid] : o_strm;
          acc3 = dot4(xo,          hB, acc3);
          g_cur = g_nxt;
        }
        acc0 += __shfl_xor(acc0, 1);
        acc1 += __shfl_xor(acc1, 1);
        acc2 += __shfl_xor(acc2, 1);
        acc3 += __shfl_xor(acc3, 1);
        float ci = sigm(acc0), cf = sigm(acc1), cg = tanh_f(acc2), co = sigm(acc3);
        c = cf * c + ci * cg;
        hn = co * tanh_f(c);
      }
      __syncthreads();                        // all reads of hsh complete
      if (act && s2 == 0){
        ((_Float16*)hsh)[(((r0 >> 6) * 36) + ((r0 >> 1) & 31)) * 2 + (r0 & 1)] = (_Float16)hn;
        Hws[t * H_ + r0] = hn;
      }
      __syncthreads();                        // Hws/hsh writes drained (vmcnt0 at barrier)
      if (tid == 512){
        // publish from an idle wave: wbl2+store stall hides under next step's dots
        __threadfence();
        st_rel(prog_h, t + 1);
      }
      if (act) a_cur = a_nxt;
    }
  } else if (bid <= NPREB){
    // ------------------------- PRE workers -------------------------
    float* wrow = sm.p.wrow;
    float* hbuf = sm.p.hbuf;
    const int w9 = bid - 1;
    const int grp = w9 & (NGRP - 1), ph = w9 >> 4;
    const int rbase = grp * RPB;
    const int nrows = (rbase + RPB <= CMROWS) ? RPB : (CMROWS - rbase);
    for (int id = tid; id < nrows * H_; id += 1024){
      int lr = id >> 8, k = id & 255;
      wrow[lr * WSTR + k] = CMR[(size_t)rbase * H_ + id];
    }
    __syncthreads();
    int hflag = 0;
    for (int t = ph; t < T_; t += 2){
      if (tid < H_){
        if (hflag < t + 1){
          while ((hflag = ld_acq(prog_h)) < t + 1) __builtin_amdgcn_s_sleep(8);
        }
        hbuf[tid] = Hws[t * H_ + tid];
      }
      __syncthreads();
      if (tid < nrows){
        // exact same fma chain as old k_pre: a = fma(w_k, h_k, a), k ascending
        const float* wr = &wrow[tid * WSTR];
        float a = 0.f;
        #pragma unroll 8
        for (int k = 0; k < H_; ++k) a += wr[k] * hbuf[k];
        PRE[(size_t)t * PSTR + rbase + tid] = a;
      }
      __syncthreads();                        // PRE writes drained; hbuf reads done
      if (tid == 0){
        __threadfence();
        (void)__hip_atomic_fetch_add(&pre_done[t], 1, __ATOMIC_RELEASE,
                                     __HIP_MEMORY_SCOPE_AGENT);
      }
    }
  } else {
    // ------------------------- ENT consumer -------------------------
    EntS& E = sm.e;
    unsigned* Gsh = E.Gsh;
    auto& hsh2 = E.hsh2;
    auto& Hld = E.Hld; auto& Dld = E.Dld; auto& Wld = E.Wld; auto& Vld = E.Vld;
    auto& EXs = E.EXs;
    float* Ssh = E.Ssh; float* DSH = E.DSH;
    auto& red = E.red; float* sc = E.sc;

    for (int id = tid; id < E_ * 128; id += 1024){
      int j = id >> 7, cx = id & 127;
      Gsh[j * 132 + cx] = packh2(GI[j * H_ + 2 * cx], GI[j * H_ + 2 * cx + 1]);
    }
    if (tid < E_){
      float ssum = 0.f;
      for (int k = 0; k < H_; ++k) ssum += GI[tid * H_ + k];
      Ssh[tid] = ssum;
      DSH[tid] = dist_init[tid];
    }
    const float wd = wdW[0], wdb = wdB[0], bdel = WdeltaB[0];
    const float wentb = WentB[0], wrb = WrB[0];
    int eid = ids[0];
    int eidn = ids[1];
    float e_k = 0.f, m_k = 0.f, web = 0.f;
    float l_i = 0.f, wlb = 0.f;
    // wait for step-0 streams (full acquire: syncs with all 16 group workers)
    while (ld_acq(&pre_done[0]) < NGRP) __builtin_amdgcn_s_sleep(2);
    if (tid < H_){
      e_k = ENTS[eid * H_ + tid];
      m_k = MST[eid * H_ + tid];
      web = We_b[tid];
      float h0 = Hws[tid];
      Hld[0][tid] = h0;
      ((_Float16*)&hsh2[0][0])[tid] = (_Float16)h0;
      Dld[0][tid] = PRE[tid];
      Wld[0][tid] = PRE[256 + tid];
      Vld[0][tid] = PRE[512 + tid];
    }
    if (tid < 25){ l_i = LST[eid * 32 + tid]; wlb = Wlen_b[tid]; }
    if (tid >= 256 && tid < 308) EXs[0][tid - 256] = PRE[768 + (tid - 256)];
    int dv = NGRP;
    if (T_ > 1) dv = ld_rlx(&pre_done[1]);    // pre-sample, settled by t=0's gate
    __syncthreads();

    const int jrow = tid >> 4, sl = tid & 15;
    const int wave = tid >> 6;

    for (int t = 0; t < T_; ++t){
      const int par = t & 1;
      float Hn = 0.f, Dn = 0.f, Wn = 0.f, Vn = 0.f, EXn = 0.f;
      if (t + 1 < T_){
        // gate the t+1 prefetch; fast path uses last step's relaxed sample so
        // no vmcnt(0) lands in the hot loop. PRE/Hws per-t regions are
        // cache-line disjoint (PSTR=832) => first-touch loads come from LLC.
        if (tid < 320 && dv < NGRP){
          while (ld_acq(&pre_done[t + 1]) < NGRP) __builtin_amdgcn_s_sleep(2);
        }
        if (tid < H_){
          Hn = Hws[(t + 1) * H_ + tid];
          const float* p = &PRE[(size_t)(t + 1) * PSTR];
          Dn = p[tid]; Wn = p[256 + tid]; Vn = p[512 + tid];
        } else if (tid < 308){
          EXn = PRE[(size_t)(t + 1) * PSTR + 768 + (tid - 256)];
        }
        if (tid < 320)
          dv = (t + 2 < T_) ? ld_rlx(&pre_done[t + 2]) : NGRP;
      }
      const int eid2 = ids[(t + 2 < T_) ? (t + 2) : (T_ - 1)];
      const bool swr = (eidn != eid);
      float e2 = 0.f, m2 = 0.f, l2 = 0.f;
      if (swr){
        if (tid < H_){ e2 = ENTS[eidn * H_ + tid]; m2 = MST[eidn * H_ + tid]; }
        if (tid < 25)  l2 = LST[eidn * 32 + tid];
      }
      // pred_e dots on OLD G
      float pe = 0.f;
      {
        uint4 g0 = *(const uint4*)&Gsh[jrow * 132 + sl * 8];
        uint4 g1 = *(const uint4*)&Gsh[jrow * 132 + sl * 8 + 4];
        uint4 h0 = *(const uint4*)&hsh2[par][sl * 8];
        uint4 h1 = *(const uint4*)&hsh2[par][sl * 8 + 4];
        pe = fdot2u(g0.x, h0.x, pe); pe = fdot2u(g0.y, h0.y, pe);
        pe = fdot2u(g0.z, h0.z, pe); pe = fdot2u(g0.w, h0.w, pe);
        pe = fdot2u(g1.x, h1.x, pe); pe = fdot2u(g1.y, h1.y, pe);
        pe = fdot2u(g1.z, h1.z, pe); pe = fdot2u(g1.w, h1.w, pe);
        pe += __shfl_xor(pe, 1); pe += __shfl_xor(pe, 2);
        pe += __shfl_xor(pe, 4); pe += __shfl_xor(pe, 8);
      }
      if (sl == 0){
        float dist = DSH[jrow] - (float)t;
        out[(size_t)t * OSTRIDE + 2 + jrow] = pe + (dist * wd + wdb) * Ssh[jrow] + wentb;
      }
      // delta dot + sum(Hw) partials
      if (tid < H_){
        float pd = e_k * Dld[par][tid];
        float pw = Wld[par][tid];
        #pragma unroll
        for (int m = 1; m < 64; m <<= 1){ pd += __shfl_xor(pd, m); pw += __shfl_xor(pw, m); }
        if ((tid & 63) == 0){ red[wave][0] = pd; red[wave][1] = pw; }
      }
      __syncthreads();                                        // B1
      if (tid == 0){
        float sd = red[0][0] + red[1][0] + red[2][0] + red[3][0];
        float swt = red[0][1] + red[1][1] + red[2][1] + red[3][1];
        sc[0] = sigm(sd + bdel);
        sc[1] = swt;
      }
      __syncthreads();                                        // B2
      const float del = sc[0];
      float u = 0.f;
      if (tid < H_){
        u = del * e_k + (1.0f - del) * Hld[par][tid];
        float pu = u * u;
        #pragma unroll
        for (int m = 1; m < 64; m <<= 1) pu += __shfl_xor(pu, m);
        if ((tid & 63) == 0) red[wave][0] = pu;
      }
      __syncthreads();                                        // B3
      if (tid == 0)
        sc[2] = __builtin_amdgcn_rsqf(red[0][0] + red[1][0] + red[2][0] + red[3][0]);
      __syncthreads();                                        // B4
      const float rn = sc[2];
      float un = 0.f, mn = 0.f;
      if (tid < H_){
        un = u * rn;
        ENTS[eid * H_ + tid] = un;
        mn = (del * m_k + (1.0f - del) * Vld[par][tid]) * rn;
        MST[eid * H_ + tid] = mn;
        float z = Hld[par][tid] + m_k + web;                  // old M (= We@e_cur)
        Zb[(size_t)t * H_ + tid] = f2bf(z);
      }
      if (tid < 128){
        unsigned gp = Gsh[eid * 132 + tid];
        half2v g = __builtin_bit_cast(half2v, gp);
        float gl = (del * (float)g.x + (1.0f - del) * Wld[par][2 * tid    ]) * rn;
        float gh = (del * (float)g.y + (1.0f - del) * Wld[par][2 * tid + 1]) * rn;
        Gsh[eid * 132 + tid] = packh2(gl, gh);
      }
      float ln = 0.f;
      if (tid < 25){
        out[(size_t)t * OSTRIDE + 66 + tid] = EXs[par][2 + tid] + l_i + wlb;
        ln = (del * l_i + (1.0f - del) * EXs[par][27 + tid]) * rn;
        LST[eid * 32 + tid] = ln;
      }
      if (tid < 2) out[(size_t)t * OSTRIDE + tid] = EXs[par][tid] + wrb;
      if (tid == 0){
        Ssh[eid] = (del * Ssh[eid] + (1.0f - del) * sc[1]) * rn;
        DSH[eid] = (float)t;
      }
      // stage next buffers
      if (t + 1 < T_){
        if (tid < H_){
          Hld[1 - par][tid] = Hn; Dld[1 - par][tid] = Dn;
          Wld[1 - par][tid] = Wn; Vld[1 - par][tid] = Vn;
          ((_Float16*)&hsh2[1 - par][0])[tid] = (_Float16)Hn;
        } else if (tid < 308){
          EXs[1 - par][tid - 256] = EXn;
        }
      }
      // rotate entity registers
      if (tid < H_){ e_k = swr ? e2 : un; m_k = swr ? m2 : mn; }
      if (tid < 25)  l_i = swr ? l2 : ln;
      eid = eidn; eidn = eid2;
      __syncthreads();                                        // B5
    }
  }
}

// ---------------------------------------------------------------------------
// k_gemm: out[t][91+v] = out_W @ z_t + out_b, bf16 MFMA, 128x128 tiles.
// ---------------------------------------------------------------------------
__global__ __launch_bounds__(256) void k_gemm(const unsigned short* __restrict__ OWB,
                                              const unsigned short* __restrict__ Zb,
                                              const float* __restrict__ out_b,
                                              float* __restrict__ out){
  __shared__ __align__(16) unsigned short Ash[128 * 72];
  __shared__ __align__(16) unsigned short Bsh[128 * 72];
  const int t0 = blockIdx.x * 128;
  const int v0 = blockIdx.y * 128;
  const int tid = threadIdx.x;
  const int lane = tid & 63, w = tid >> 6;
  const int mb = (w & 1) * 64, nb = (w >> 1) * 64;
  const int q = lane >> 4, fr = lane & 15;
  floatx4 acc[4][4];
  #pragma unroll
  for (int a = 0; a < 4; ++a)
    #pragma unroll
    for (int b = 0; b < 4; ++b) acc[a][b] = (floatx4){0.f, 0.f, 0.f, 0.f};
  for (int kt = 0; kt < 4; ++kt){
    if (kt) __syncthreads();
    #pragma unroll
    for (int it = 0; it < 4; ++it){
      int task = it * 256 + tid;
      int r = task >> 3, c8 = task & 7;
      int gk = kt * 64 + c8 * 8;
      uint4 av;
      if (v0 + r < V_) av = *(const uint4*)&OWB[(size_t)(v0 + r) * H_ + gk];
      else { av.x = 0; av.y = 0; av.z = 0; av.w = 0; }
      *(uint4*)&Ash[r * 72 + c8 * 8] = av;
      uint4 bv = *(const uint4*)&Zb[(size_t)(t0 + r) * H_ + gk];
      *(uint4*)&Bsh[r * 72 + c8 * 8] = bv;
    }
    __syncthreads();
    #pragma unroll
    for (int ks = 0; ks < 2; ++ks){
      short8v af[4], bf[4];
      #pragma unroll
      for (int mi = 0; mi < 4; ++mi)
        af[mi] = *(const short8v*)&Ash[(mb + mi * 16 + fr) * 72 + ks * 32 + q * 8];
      #pragma unroll
      for (int ni = 0; ni < 4; ++ni)
        bf[ni] = *(const short8v*)&Bsh[(nb + ni * 16 + fr) * 72 + ks * 32 + q * 8];
      #pragma unroll
      for (int mi = 0; mi < 4; ++mi)
        #pragma unroll
        for (int ni = 0; ni < 4; ++ni)
          acc[mi][ni] = __builtin_amdgcn_mfma_f32_16x16x32_bf16(af[mi], bf[ni],
                                                                acc[mi][ni], 0, 0, 0);
    }
  }
  #pragma unroll
  for (int mi = 0; mi < 4; ++mi){
    #pragma unroll
    for (int ni = 0; ni < 4; ++ni){
      int tt = t0 + nb + ni * 16 + fr;
      int vv = v0 + mb + mi * 16 + q * 4;
      float* op = out + (size_t)tt * OSTRIDE + 91 + vv;
      #pragma unroll
      for (int r2 = 0; r2 < 4; ++r2){
        int v = vv + r2;
        if (v < V_) op[r2] = acc[mi][ni][r2] + out_b[v];
      }
    }
  }
}

// ---------------------------------------------------------------------------
extern "C" void kernel_launch(void* const* d_in, const int* in_sizes, int n_in,
                              void* d_out, int out_size, void* d_ws, size_t ws_size,
                              hipStream_t stream){
  (void)in_sizes; (void)n_in; (void)out_size; (void)ws_size;
  const int*   tokens  = (const int*)d_in[0];
  const int*   eids    = (const int*)d_in[1];
  const float* emb     = (const float*)d_in[2];
  const float* W_ih    = (const float*)d_in[3];
  const float* W_hh    = (const float*)d_in[4];
  const float* b_ih    = (const float*)d_in[5];
  const float* b_hh    = (const float*)d_in[6];
  const float* out_W   = (const float*)d_in[7];
  const float* out_b   = (const float*)d_in[8];
  const float* r_emb   = (const float*)d_in[9];
  const float* Wr_W    = (const float*)d_in[10];
  const float* Wr_b    = (const float*)d_in[11];
  const float* Wlen_W  = (const float*)d_in[12];
  const float* Wlen_b  = (const float*)d_in[13];
  const float* Went_W  = (const float*)d_in[14];
  const float* Went_b  = (const float*)d_in[15];
  const float* wdist_W = (const float*)d_in[16];
  const float* wdist_b = (const float*)d_in[17];
  const float* Wdelta_W= (const float*)d_in[18];
  const float* Wdelta_b= (const float*)d_in[19];
  const float* We_W    = (const float*)d_in[20];
  const float* We_b    = (const float*)d_in[21];
  const float* E0      = (const float*)d_in[22];
  const float* dist0   = (const float*)d_in[23];
  float* out = (float*)d_out;

  char* ws = (char*)d_ws;
  size_t off = 0;
  auto alloc = [&](size_t bytes) -> void* {
    void* p = ws + off;
    off += (bytes + 255) & ~(size_t)255;
    return p;
  };
  float* WT    = (float*)alloc(sizeof(float) * H_ * G4_);
  float* A4    = (float*)alloc(sizeof(float) * (size_t)T_ * H_ * 4);
  unsigned* WP = (unsigned*)alloc(sizeof(unsigned) * 32 * 1024 * 4);
  float* Hws   = (float*)alloc(sizeof(float) * (size_t)T_ * H_);
  float* CMR   = (float*)alloc(sizeof(float) * CMROWS * H_);
  float* PRE   = (float*)alloc(sizeof(float) * (size_t)T_ * PSTR);
  float* ENTS  = (float*)alloc(sizeof(float) * E_ * H_);
  float* MST   = (float*)alloc(sizeof(float) * E_ * H_);
  float* LST   = (float*)alloc(sizeof(float) * E_ * 32);
  float* GI    = (float*)alloc(sizeof(float) * E_ * H_);
  unsigned short* Zb  = (unsigned short*)alloc(sizeof(short) * (size_t)T_ * H_);
  unsigned short* OWB = (unsigned short*)alloc(sizeof(short) * (size_t)V_ * H_);
  int* pre_done = (int*)alloc(sizeof(int) * T_ + 256);   // prog_h tails the array
  int* prog_h   = pre_done + T_;

  hipMemsetAsync(pre_done, 0, sizeof(int) * T_ + 256, stream);
  hipLaunchKernelGGL(k_prep, dim3(4096), dim3(256), 0, stream,
                     out_W, W_ih, W_hh, OWB, WT, WP);
  hipLaunchKernelGGL(k_cm, dim3(512), dim3(256), 0, stream,
                     Wdelta_W, Went_W, We_W, r_emb, Wr_W, Wlen_W, CMR);
  hipLaunchKernelGGL(k_init, dim3(256), dim3(256), 0, stream,
                     E0, Went_W, We_W, Wlen_W, GI, MST, LST, ENTS);
  hipLaunchKernelGGL(k_a, dim3(T_ / 8), dim3(1024), 0, stream,
                     tokens, emb, WT, b_ih, b_hh, A4);
  hipLaunchKernelGGL(k_pipe, dim3(2 + NPREB), dim3(1024), 0, stream,
                     (const uint4*)WP, (const floatx4*)A4, Hws, CMR, PRE,
                     eids, GI, dist0, We_b, Wlen_b,
                     wdist_W, wdist_b, Wdelta_b, Went_b, Wr_b,
                     ENTS, MST, LST, Zb, out, prog_h, pre_done);
  hipLaunchKernelGGL(k_gemm, dim3(16, 393), dim3(256), 0, stream,
                     OWB, Zb, out_b, out);
}

// Round 2
// 4444.184 us; speedup vs baseline: 5.3837x; 5.3837x over previous
//
#include <hip/hip_runtime.h>
#include <cstdint>
#include <cstddef>

#define V_  50257
#define H_  256
#define E_  64
#define T_  2048
#define G4_ 1024
#define OSTRIDE 50348
#define CMROWS 820
#define PSTR 832          // PRE row stride: per-t regions cache-line disjoint
#define NGRP 16           // PRE row groups
#define RPB 52            // rows per group (16*52 = 832 >= 820)
#define NPREB 32          // PRE worker blocks: 16 groups x 2 time parities
#define WSTR 257          // LDS stride for worker weight rows (conflict-free)

typedef __attribute__((ext_vector_type(2))) _Float16 half2v;
typedef __attribute__((ext_vector_type(8))) short short8v;
typedef __attribute__((ext_vector_type(4))) float floatx4;

__device__ __forceinline__ float fdot2u(unsigned a, unsigned b, float acc){
  return __builtin_amdgcn_fdot2(__builtin_bit_cast(half2v, a),
                                __builtin_bit_cast(half2v, b), acc, false);
}
__device__ __forceinline__ unsigned packh2(float a, float b){
  half2v h; h.x = (_Float16)a; h.y = (_Float16)b;
  return __builtin_bit_cast(unsigned, h);
}
__device__ __forceinline__ unsigned short f2bf(float f){
  unsigned u = __builtin_bit_cast(unsigned, f);
  u += 0x7fffu + ((u >> 16) & 1u);
  return (unsigned short)(u >> 16);
}
__device__ __forceinline__ float sigm(float x){
  return __builtin_amdgcn_rcpf(1.0f + __expf(-x));
}
__device__ __forceinline__ float tanh_f(float x){
  float e = __expf(2.0f * x);
  return (e - 1.0f) * __builtin_amdgcn_rcpf(e + 1.0f);
}
__device__ __forceinline__ float dot4(uint4 w, uint4 h, float acc){
  acc = fdot2u(w.x, h.x, acc); acc = fdot2u(w.y, h.y, acc);
  acc = fdot2u(w.z, h.z, acc); acc = fdot2u(w.w, h.w, acc);
  return acc;
}

// Fence-free cross-XCD handshake: relaxed agent-scope atomics compile to
// plain sc1 loads/stores (bypass L1/L2 to the coherent LLC) with NO cache-wide
// buffer_inv / buffer_wbl2. Ordering: producer's __syncthreads drains vmcnt(0)
// (payload LLC-acked) before the flag fetch_add is issued.
__device__ __forceinline__ int ldi_rlx(int* p){
  return __hip_atomic_load(p, __ATOMIC_RELAXED, __HIP_MEMORY_SCOPE_AGENT);
}
__device__ __forceinline__ float ldf_rlx(const float* p){
  return __hip_atomic_load(p, __ATOMIC_RELAXED, __HIP_MEMORY_SCOPE_AGENT);
}
__device__ __forceinline__ void stf_rlx(float* p, float v){
  __hip_atomic_store(p, v, __ATOMIC_RELAXED, __HIP_MEMORY_SCOPE_AGENT);
}
__device__ __forceinline__ void flag_add(int* p){
  (void)__hip_atomic_fetch_add(p, 1, __ATOMIC_RELAXED, __HIP_MEMORY_SCOPE_AGENT);
}

// ---------------------------------------------------------------------------
// k_prep: out_W -> bf16 (OWB), W_ih -> transposed WT [k][r], W_hh -> f16 pack WP
// ---------------------------------------------------------------------------
__global__ void k_prep(const float* __restrict__ out_W, const float* __restrict__ W_ih,
                       const float* __restrict__ W_hh,
                       unsigned short* __restrict__ OWB, float* __restrict__ WT,
                       unsigned* __restrict__ WP){
  const long n0 = (long)V_ * H_;
  const long n1 = (long)G4_ * H_;
  const long n2 = 32l * G4_;
  const long total = n0 + n1 + n2;
  for (long id = (long)blockIdx.x * blockDim.x + threadIdx.x; id < total;
       id += (long)gridDim.x * blockDim.x){
    if (id < n0){
      OWB[id] = f2bf(out_W[id]);
    } else if (id < n0 + n1){
      long i = id - n0;                 // i = k*1024 + r
      int r = (int)(i & 1023), k = (int)(i >> 10);
      WT[i] = W_ih[r * H_ + k];
    } else {
      long i = id - n0 - n1;
      int t = (int)(i & 1023), j4 = (int)(i >> 10);
      int r0 = t >> 2, s = t & 3;
      #pragma unroll
      for (int d = 0; d < 4; ++d){
        int j = j4 * 4 + d;
        int ri = j >> 5, c = j & 31;
        int grow = ri * H_ + r0;
        int k0 = s * 64 + c * 2;
        WP[(j4 * 1024 + t) * 4 + d] = packh2(W_hh[grow * H_ + k0],
                                             W_hh[grow * H_ + k0 + 1]);
      }
    }
  }
}

// ---------------------------------------------------------------------------
// k_cm: build CMR [820][256] row-major combined matrix.
// ---------------------------------------------------------------------------
__global__ void k_cm(const float* __restrict__ Wdelta, const float* __restrict__ Went,
                     const float* __restrict__ We, const float* __restrict__ r_emb,
                     const float* __restrict__ Wr, const float* __restrict__ Wlen,
                     float* __restrict__ CMR){
  const int total = CMROWS * H_;
  for (int id = blockIdx.x * blockDim.x + threadIdx.x; id < total;
       id += gridDim.x * blockDim.x){
    int r = id >> 8, k = id & 255;
    float v;
    if (r < 256)      v = Wdelta[r * H_ + k];
    else if (r < 512) v = Went[k * H_ + (r - 256)];
    else if (r < 768) v = We[(r - 512) * H_ + k];
    else if (r < 770){
      int i = r - 768; float acc = 0.f;
      for (int m = 0; m < H_; ++m) acc += r_emb[i * H_ + m] * Wr[m * H_ + k];
      v = acc;
    }
    else if (r < 795) v = Wlen[(r - 770) * 2 * H_ + k];
    else              v = Wlen[(r - 795) * 2 * H_ + H_ + k];
    CMR[r * H_ + k] = v;
  }
}

// ---------------------------------------------------------------------------
// k_init: G_init = E0@Went, M_init = E0@We^T, L_init = E0@WlenE^T, ENTS = E0
// ---------------------------------------------------------------------------
__global__ void k_init(const float* __restrict__ E0, const float* __restrict__ Went,
                       const float* __restrict__ We, const float* __restrict__ Wlen,
                       float* __restrict__ GI, float* __restrict__ MST,
                       float* __restrict__ LST, float* __restrict__ ENTS){
  const int nG = E_ * H_, nM = E_ * H_, nL = E_ * 32, nC = E_ * H_;
  const int total = nG + nM + nL + nC;
  for (int id = blockIdx.x * blockDim.x + threadIdx.x; id < total;
       id += gridDim.x * blockDim.x){
    if (id < nG){
      int j = id >> 8, i = id & 255; float a = 0.f;
      for (int k = 0; k < H_; ++k) a += E0[j * H_ + k] * Went[k * H_ + i];
      GI[id] = a;
    } else if (id < nG + nM){
      int x = id - nG; int j = x >> 8, i = x & 255; float a = 0.f;
      for (int k = 0; k < H_; ++k) a += E0[j * H_ + k] * We[i * H_ + k];
      MST[x] = a;
    } else if (id < nG + nM + nL){
      int x = id - nG - nM; int j = x >> 5, i = x & 31; float a = 0.f;
      if (i < 25)
        for (int k = 0; k < H_; ++k) a += E0[j * H_ + k] * Wlen[i * 2 * H_ + H_ + k];
      LST[x] = a;
    } else {
      int x = id - nG - nM - nL;
      ENTS[x] = E0[x];
    }
  }
}

// ---------------------------------------------------------------------------
// k_a: A4[t][r0][gate] = W_ih@emb[tok_t] + b_ih + b_hh  (8 timesteps / block)
// ---------------------------------------------------------------------------
__global__ __launch_bounds__(1024) void k_a(const int* __restrict__ tokens,
                                            const float* __restrict__ emb,
                                            const float* __restrict__ WT,
                                            const float* __restrict__ b_ih,
                                            const float* __restrict__ b_hh,
                                            float* __restrict__ A4){
  __shared__ __align__(16) float xs[H_][8];
  const int t0 = blockIdx.x * 8;
  const int tid = threadIdx.x;
  for (int id = tid; id < 8 * H_; id += 1024){
    int k = id >> 3, tl = id & 7;
    xs[k][tl] = emb[(size_t)tokens[t0 + tl] * H_ + k];
  }
  __syncthreads();
  const int r = tid;
  const float base = b_ih[r] + b_hh[r];
  float acc[8];
  #pragma unroll
  for (int i = 0; i < 8; ++i) acc[i] = base;
  for (int k = 0; k < H_; ++k){
    float w = WT[k * G4_ + r];
    floatx4 x0 = *(const floatx4*)&xs[k][0];
    floatx4 x1 = *(const floatx4*)&xs[k][4];
    acc[0] += w * x0.x; acc[1] += w * x0.y; acc[2] += w * x0.z; acc[3] += w * x0.w;
    acc[4] += w * x1.x; acc[5] += w * x1.y; acc[6] += w * x1.z; acc[7] += w * x1.w;
  }
  const int r0 = r & 255, g = r >> 8;
  #pragma unroll
  for (int tl = 0; tl < 8; ++tl)
    A4[(((t0 + tl) * H_ + r0) << 2) + g] = acc[tl];
}

// ---------------------------------------------------------------------------
// k_pipe: fused producer/consumer pipeline over t. ALL BLOCKS 512 THREADS
// (8 waves -> 256-VGPR cap: the LSTM weight set stays register-resident).
//   block 0        : LSTM (identical math/mapping to the old k_lstm)
//   blocks 1..32   : PRE workers (group g rows [52g,52g+52), parity-split t)
//   block 33       : ENT scan (512-thread variant; math identical, pred_e
//                    reduction = 64 rows x 8 lanes)
// 34 blocks all co-resident => no deadlock.
// ---------------------------------------------------------------------------
struct LstmS { unsigned hsh[4 * 36]; uint4 olds[7 * 512]; };           // 57920 B
struct PreS  { float wrow[RPB * WSTR]; float hbuf[H_]; };              // 54480 B
struct EntS  {
  unsigned Gsh[E_ * 132];
  unsigned hsh2[2][128];
  float Hld[2][H_], Dld[2][H_], Wld[2][H_], Vld[2][H_];
  float EXs[2][64];
  float Ssh[E_], DSH[E_];
  float red[8][2];
  float sc[4];
};                                                                     // 44112 B
union PipeS { LstmS l; PreS p; EntS e; };

__global__ __launch_bounds__(512, 1) void k_pipe(
    const uint4* __restrict__ WP4, const floatx4* __restrict__ A4,
    float* Hws, const float* __restrict__ CMR, float* PRE,
    const int* __restrict__ ids, const float* __restrict__ GI,
    const float* __restrict__ dist_init, const float* __restrict__ We_b,
    const float* __restrict__ Wlen_b, const float* __restrict__ wdW,
    const float* __restrict__ wdB, const float* __restrict__ WdeltaB,
    const float* __restrict__ WentB, const float* __restrict__ WrB,
    float* __restrict__ ENTS, float* __restrict__ MST, float* __restrict__ LST,
    unsigned short* __restrict__ Zb, float* __restrict__ out,
    int* prog_h, int* pre_done)
{
  __shared__ PipeS sm;
  const int tid = threadIdx.x;
  const int bid = blockIdx.x;

  if (bid == 0){
    // ------------------------- LSTM producer (verbatim old k_lstm) ---------
    unsigned* hsh = sm.l.hsh;
    uint4* olds = sm.l.olds;
    const int r0 = tid >> 1, s2 = tid & 1;
    const int tA = r0 * 4 + 2 * s2;
    const int tB = tA + 1;
    const int sA = 2 * s2;

    uint4 wA[32], wB[16];
    #pragma unroll
    for (int j4 = 0; j4 < 32; ++j4) wA[j4] = WP4[j4 * 1024 + tA];
    #pragma unroll
    for (int j4 = 0; j4 < 16; ++j4) wB[j4] = WP4[j4 * 1024 + tB];
    #pragma unroll
    for (int j4 = 24; j4 < 31; ++j4) olds[(j4 - 24) * 512 + tid] = WP4[j4 * 1024 + tB];
    if (tid < 144) hsh[tid] = 0u;

    const uint4* gsrc = &WP4[16 * 1024 + tB];   // gsrc[cc*1024] = j4 16+cc
    uint4 g_cur = gsrc[0];                      // gate-g cc0 (pipelined)
    float c = 0.0f;
    floatx4 a_cur = A4[r0];
    floatx4 a_nxt = a_cur;
    __syncthreads();

    for (int t = 0; t < T_; ++t){
      if (t + 1 < T_) a_nxt = A4[(t + 1) * H_ + r0];
      uint4 o_strm = gsrc[15 * 1024];           // gate-o cc7 (j4=31)
      float acc0 = a_cur.x * 0.5f, acc1 = a_cur.y * 0.5f;
      float acc2 = a_cur.z * 0.5f, acc3 = a_cur.w * 0.5f;
      #pragma unroll
      for (int cc = 0; cc < 8; ++cc){
        uint4 g_nxt = gsrc[((cc < 7) ? (cc + 1) : 0) * 1024];
        uint4 hA = *(const uint4*)&hsh[sA * 36 + cc * 4];
        uint4 hB = *(const uint4*)&hsh[sA * 36 + 36 + cc * 4];
        acc0 = dot4(wA[cc],      hA, acc0);
        acc1 = dot4(wA[8 + cc],  hA, acc1);
        acc2 = dot4(wA[16 + cc], hA, acc2);
        acc3 = dot4(wA[24 + cc], hA, acc3);
        acc0 = dot4(wB[cc],      hB, acc0);
        acc1 = dot4(wB[8 + cc],  hB, acc1);
        acc2 = dot4(g_cur,       hB, acc2);
        uint4 xo = (cc < 7) ? olds[cc * 512 + tid] : o_strm;
        acc3 = dot4(xo,          hB, acc3);
        g_cur = g_nxt;
      }
      acc0 += __shfl_xor(acc0, 1);
      acc1 += __shfl_xor(acc1, 1);
      acc2 += __shfl_xor(acc2, 1);
      acc3 += __shfl_xor(acc3, 1);
      float ci = sigm(acc0), cf = sigm(acc1), cg = tanh_f(acc2), co = sigm(acc3);
      c = cf * c + ci * cg;
      float hn = co * tanh_f(c);
      __syncthreads();                        // all reads of hsh complete
      if (s2 == 0){
        ((_Float16*)hsh)[(((r0 >> 6) * 36) + ((r0 >> 1) & 31)) * 2 + (r0 & 1)] = (_Float16)hn;
        stf_rlx(&Hws[t * H_ + r0], hn);       // sc1: straight to LLC
      }
      __syncthreads();                        // vmcnt(0): h stores LLC-acked
      if (tid == 0) flag_add(prog_h);         // fire-and-forget publish
      a_cur = a_nxt;
    }
  } else if (bid <= NPREB){
    // ------------------------- PRE workers -------------------------
    float* wrow = sm.p.wrow;
    float* hbuf = sm.p.hbuf;
    const int w9 = bid - 1;
    const int grp = w9 & (NGRP - 1), ph = w9 >> 4;
    const int rbase = grp * RPB;
    const int nrows = (rbase + RPB <= CMROWS) ? RPB : (CMROWS - rbase);
    for (int id = tid; id < nrows * H_; id += 512){
      int lr = id >> 8, k = id & 255;
      wrow[lr * WSTR + k] = CMR[(size_t)rbase * H_ + id];
    }
    __syncthreads();
    for (int t = ph; t < T_; t += 2){
      if (tid == 0){
        while (ldi_rlx(prog_h) < t + 1) __builtin_amdgcn_s_sleep(8);
      }
      __syncthreads();
      if (tid < H_) hbuf[tid] = ldf_rlx(&Hws[t * H_ + tid]);
      __syncthreads();
      if (tid < nrows){
        // exact same fma chain as old k_pre: a = fma(w_k, h_k, a), k ascending
        const float* wr = &wrow[tid * WSTR];
        float a = 0.f;
        #pragma unroll 8
        for (int k = 0; k < H_; ++k) a += wr[k] * hbuf[k];
        stf_rlx(&PRE[(size_t)t * PSTR + rbase + tid], a);
      }
      __syncthreads();                        // vmcnt(0): PRE stores LLC-acked
      if (tid == 0) flag_add(&pre_done[t]);
    }
  } else {
    // ------------------------- ENT consumer (512-thread variant) ----------
    EntS& E = sm.e;
    unsigned* Gsh = E.Gsh;
    auto& hsh2 = E.hsh2;
    auto& Hld = E.Hld; auto& Dld = E.Dld; auto& Wld = E.Wld; auto& Vld = E.Vld;
    auto& EXs = E.EXs;
    float* Ssh = E.Ssh; float* DSH = E.DSH;
    auto& red = E.red; float* sc = E.sc;

    for (int id = tid; id < E_ * 128; id += 512){
      int j = id >> 7, cx = id & 127;
      Gsh[j * 132 + cx] = packh2(GI[j * H_ + 2 * cx], GI[j * H_ + 2 * cx + 1]);
    }
    if (tid < E_){
      float ssum = 0.f;
      for (int k = 0; k < H_; ++k) ssum += GI[tid * H_ + k];
      Ssh[tid] = ssum;
      DSH[tid] = dist_init[tid];
    }
    const float wd = wdW[0], wdb = wdB[0], bdel = WdeltaB[0];
    const float wentb = WentB[0], wrb = WrB[0];
    int eid = ids[0];
    int eidn = ids[1];
    float e_k = 0.f, m_k = 0.f, web = 0.f;
    float l_i = 0.f, wlb = 0.f;
    if (tid == 0){
      while (ldi_rlx(&pre_done[0]) < NGRP) __builtin_amdgcn_s_sleep(2);
    }
    __syncthreads();
    if (tid < H_){
      e_k = ENTS[eid * H_ + tid];
      m_k = MST[eid * H_ + tid];
      web = We_b[tid];
      float h0 = ldf_rlx(&Hws[tid]);
      Hld[0][tid] = h0;
      ((_Float16*)&hsh2[0][0])[tid] = (_Float16)h0;
      Dld[0][tid] = ldf_rlx(&PRE[tid]);
      Wld[0][tid] = ldf_rlx(&PRE[256 + tid]);
      Vld[0][tid] = ldf_rlx(&PRE[512 + tid]);
    }
    if (tid < 25){ l_i = LST[eid * 32 + tid]; wlb = Wlen_b[tid]; }
    if (tid >= 256 && tid < 308) EXs[0][tid - 256] = ldf_rlx(&PRE[768 + (tid - 256)]);
    int dv = NGRP;
    if (T_ > 1) dv = ldi_rlx(&pre_done[1]);   // pre-sample one step ahead
    __syncthreads();

    const int jrow = tid >> 3, sl = tid & 7;
    const int wave = tid >> 6;

    for (int t = 0; t < T_; ++t){
      const int par = t & 1;
      float Hn = 0.f, Dn = 0.f, Wn = 0.f, Vn = 0.f, EXn = 0.f;
      if (t + 1 < T_){
        // gate the t+1 prefetch; fast path uses last step's relaxed sample.
        if (tid < 320 && dv < NGRP){
          while (ldi_rlx(&pre_done[t + 1]) < NGRP) __builtin_amdgcn_s_sleep(2);
        }
        if (tid < H_){
          Hn = ldf_rlx(&Hws[(t + 1) * H_ + tid]);
          float* p = &PRE[(size_t)(t + 1) * PSTR];
          Dn = ldf_rlx(&p[tid]); Wn = ldf_rlx(&p[256 + tid]); Vn = ldf_rlx(&p[512 + tid]);
        } else if (tid < 308){
          EXn = ldf_rlx(&PRE[(size_t)(t + 1) * PSTR + 768 + (tid - 256)]);
        }
        if (tid < 320)
          dv = (t + 2 < T_) ? ldi_rlx(&pre_done[t + 2]) : NGRP;
      }
      const int eid2 = ids[(t + 2 < T_) ? (t + 2) : (T_ - 1)];
      const bool swr = (eidn != eid);
      float e2 = 0.f, m2 = 0.f, l2 = 0.f;
      if (swr){
        if (tid < H_){ e2 = ENTS[eidn * H_ + tid]; m2 = MST[eidn * H_ + tid]; }
        if (tid < 25)  l2 = LST[eidn * 32 + tid];
      }
      // pred_e dots on OLD G: 64 rows x 8 lanes x 16 dwords
      float pe = 0.f;
      {
        const unsigned* gp = &Gsh[jrow * 132 + sl * 16];
        const unsigned* hp = &hsh2[par][sl * 16];
        uint4 g0 = *(const uint4*)&gp[0];
        uint4 g1 = *(const uint4*)&gp[4];
        uint4 g2 = *(const uint4*)&gp[8];
        uint4 g3 = *(const uint4*)&gp[12];
        uint4 h0 = *(const uint4*)&hp[0];
        uint4 h1 = *(const uint4*)&hp[4];
        uint4 h2 = *(const uint4*)&hp[8];
        uint4 h3 = *(const uint4*)&hp[12];
        pe = dot4(g0, h0, pe); pe = dot4(g1, h1, pe);
        pe = dot4(g2, h2, pe); pe = dot4(g3, h3, pe);
        pe += __shfl_xor(pe, 1); pe += __shfl_xor(pe, 2); pe += __shfl_xor(pe, 4);
      }
      if (sl == 0){
        float dist = DSH[jrow] - (float)t;
        out[(size_t)t * OSTRIDE + 2 + jrow] = pe + (dist * wd + wdb) * Ssh[jrow] + wentb;
      }
      // delta dot + sum(Hw) partials
      if (tid < H_){
        float pd = e_k * Dld[par][tid];
        float pw = Wld[par][tid];
        #pragma unroll
        for (int m = 1; m < 64; m <<= 1){ pd += __shfl_xor(pd, m); pw += __shfl_xor(pw, m); }
        if ((tid & 63) == 0){ red[wave][0] = pd; red[wave][1] = pw; }
      }
      __syncthreads();                                        // B1
      if (tid == 0){
        float sd = red[0][0] + red[1][0] + red[2][0] + red[3][0];
        float swt = red[0][1] + red[1][1] + red[2][1] + red[3][1];
        sc[0] = sigm(sd + bdel);
        sc[1] = swt;
      }
      __syncthreads();                                        // B2
      const float del = sc[0];
      float u = 0.f;
      if (tid < H_){
        u = del * e_k + (1.0f - del) * Hld[par][tid];
        float pu = u * u;
        #pragma unroll
        for (int m = 1; m < 64; m <<= 1) pu += __shfl_xor(pu, m);
        if ((tid & 63) == 0) red[wave][0] = pu;
      }
      __syncthreads();                                        // B3
      if (tid == 0)
        sc[2] = __builtin_amdgcn_rsqf(red[0][0] + red[1][0] + red[2][0] + red[3][0]);
      __syncthreads();                                        // B4
      const float rn = sc[2];
      float un = 0.f, mn = 0.f;
      if (tid < H_){
        un = u * rn;
        ENTS[eid * H_ + tid] = un;
        mn = (del * m_k + (1.0f - del) * Vld[par][tid]) * rn;
        MST[eid * H_ + tid] = mn;
        float z = Hld[par][tid] + m_k + web;                  // old M (= We@e_cur)
        Zb[(size_t)t * H_ + tid] = f2bf(z);
      }
      if (tid < 128){
        unsigned gp2 = Gsh[eid * 132 + tid];
        half2v g = __builtin_bit_cast(half2v, gp2);
        float gl = (del * (float)g.x + (1.0f - del) * Wld[par][2 * tid    ]) * rn;
        float gh = (del * (float)g.y + (1.0f - del) * Wld[par][2 * tid + 1]) * rn;
        Gsh[eid * 132 + tid] = packh2(gl, gh);
      }
      float ln = 0.f;
      if (tid < 25){
        out[(size_t)t * OSTRIDE + 66 + tid] = EXs[par][2 + tid] + l_i + wlb;
        ln = (del * l_i + (1.0f - del) * EXs[par][27 + tid]) * rn;
        LST[eid * 32 + tid] = ln;
      }
      if (tid < 2) out[(size_t)t * OSTRIDE + tid] = EXs[par][tid] + wrb;
      if (tid == 0){
        Ssh[eid] = (del * Ssh[eid] + (1.0f - del) * sc[1]) * rn;
        DSH[eid] = (float)t;
      }
      // stage next buffers
      if (t + 1 < T_){
        if (tid < H_){
          Hld[1 - par][tid] = Hn; Dld[1 - par][tid] = Dn;
          Wld[1 - par][tid] = Wn; Vld[1 - par][tid] = Vn;
          ((_Float16*)&hsh2[1 - par][0])[tid] = (_Float16)Hn;
        } else if (tid < 308){
          EXs[1 - par][tid - 256] = EXn;
        }
      }
      // rotate entity registers
      if (tid < H_){ e_k = swr ? e2 : un; m_k = swr ? m2 : mn; }
      if (tid < 25)  l_i = swr ? l2 : ln;
      eid = eidn; eidn = eid2;
      __syncthreads();                                        // B5
    }
  }
}

// ---------------------------------------------------------------------------
// k_gemm: out[t][91+v] = out_W @ z_t + out_b, bf16 MFMA, 128x128 tiles.
// ---------------------------------------------------------------------------
__global__ __launch_bounds__(256) void k_gemm(const unsigned short* __restrict__ OWB,
                                              const unsigned short* __restrict__ Zb,
                                              const float* __restrict__ out_b,
                                              float* __restrict__ out){
  __shared__ __align__(16) unsigned short Ash[128 * 72];
  __shared__ __align__(16) unsigned short Bsh[128 * 72];
  const int t0 = blockIdx.x * 128;
  const int v0 = blockIdx.y * 128;
  const int tid = threadIdx.x;
  const int lane = tid & 63, w = tid >> 6;
  const int mb = (w & 1) * 64, nb = (w >> 1) * 64;
  const int q = lane >> 4, fr = lane & 15;
  floatx4 acc[4][4];
  #pragma unroll
  for (int a = 0; a < 4; ++a)
    #pragma unroll
    for (int b = 0; b < 4; ++b) acc[a][b] = (floatx4){0.f, 0.f, 0.f, 0.f};
  for (int kt = 0; kt < 4; ++kt){
    if (kt) __syncthreads();
    #pragma unroll
    for (int it = 0; it < 4; ++it){
      int task = it * 256 + tid;
      int r = task >> 3, c8 = task & 7;
      int gk = kt * 64 + c8 * 8;
      uint4 av;
      if (v0 + r < V_) av = *(const uint4*)&OWB[(size_t)(v0 + r) * H_ + gk];
      else { av.x = 0; av.y = 0; av.z = 0; av.w = 0; }
      *(uint4*)&Ash[r * 72 + c8 * 8] = av;
      uint4 bv = *(const uint4*)&Zb[(size_t)(t0 + r) * H_ + gk];
      *(uint4*)&Bsh[r * 72 + c8 * 8] = bv;
    }
    __syncthreads();
    #pragma unroll
    for (int ks = 0; ks < 2; ++ks){
      short8v af[4], bf[4];
      #pragma unroll
      for (int mi = 0; mi < 4; ++mi)
        af[mi] = *(const short8v*)&Ash[(mb + mi * 16 + fr) * 72 + ks * 32 + q * 8];
      #pragma unroll
      for (int ni = 0; ni < 4; ++ni)
        bf[ni] = *(const short8v*)&Bsh[(nb + ni * 16 + fr) * 72 + ks * 32 + q * 8];
      #pragma unroll
      for (int mi = 0; mi < 4; ++mi)
        #pragma unroll
        for (int ni = 0; ni < 4; ++ni)
          acc[mi][ni] = __builtin_amdgcn_mfma_f32_16x16x32_bf16(af[mi], bf[ni],
                                                                acc[mi][ni], 0, 0, 0);
    }
  }
  #pragma unroll
  for (int mi = 0; mi < 4; ++mi){
    #pragma unroll
    for (int ni = 0; ni < 4; ++ni){
      int tt = t0 + nb + ni * 16 + fr;
      int vv = v0 + mb + mi * 16 + q * 4;
      float* op = out + (size_t)tt * OSTRIDE + 91 + vv;
      #pragma unroll
      for (int r2 = 0; r2 < 4; ++r2){
        int v = vv + r2;
        if (v < V_) op[r2] = acc[mi][ni][r2] + out_b[v];
      }
    }
  }
}

// ---------------------------------------------------------------------------
extern "C" void kernel_launch(void* const* d_in, const int* in_sizes, int n_in,
                              void* d_out, int out_size, void* d_ws, size_t ws_size,
                              hipStream_t stream){
  (void)in_sizes; (void)n_in; (void)out_size; (void)ws_size;
  const int*   tokens  = (const int*)d_in[0];
  const int*   eids    = (const int*)d_in[1];
  const float* emb     = (const float*)d_in[2];
  const float* W_ih    = (const float*)d_in[3];
  const float* W_hh    = (const float*)d_in[4];
  const float* b_ih    = (const float*)d_in[5];
  const float* b_hh    = (const float*)d_in[6];
  const float* out_W   = (const float*)d_in[7];
  const float* out_b   = (const float*)d_in[8];
  const float* r_emb   = (const float*)d_in[9];
  const float* Wr_W    = (const float*)d_in[10];
  const float* Wr_b    = (const float*)d_in[11];
  const float* Wlen_W  = (const float*)d_in[12];
  const float* Wlen_b  = (const float*)d_in[13];
  const float* Went_W  = (const float*)d_in[14];
  const float* Went_b  = (const float*)d_in[15];
  const float* wdist_W = (const float*)d_in[16];
  const float* wdist_b = (const float*)d_in[17];
  const float* Wdelta_W= (const float*)d_in[18];
  const float* Wdelta_b= (const float*)d_in[19];
  const float* We_W    = (const float*)d_in[20];
  const float* We_b    = (const float*)d_in[21];
  const float* E0      = (const float*)d_in[22];
  const float* dist0   = (const float*)d_in[23];
  float* out = (float*)d_out;

  char* ws = (char*)d_ws;
  size_t off = 0;
  auto alloc = [&](size_t bytes) -> void* {
    void* p = ws + off;
    off += (bytes + 255) & ~(size_t)255;
    return p;
  };
  float* WT    = (float*)alloc(sizeof(float) * H_ * G4_);
  float* A4    = (float*)alloc(sizeof(float) * (size_t)T_ * H_ * 4);
  unsigned* WP = (unsigned*)alloc(sizeof(unsigned) * 32 * 1024 * 4);
  float* Hws   = (float*)alloc(sizeof(float) * (size_t)T_ * H_);
  float* CMR   = (float*)alloc(sizeof(float) * CMROWS * H_);
  float* PRE   = (float*)alloc(sizeof(float) * (size_t)T_ * PSTR);
  float* ENTS  = (float*)alloc(sizeof(float) * E_ * H_);
  float* MST   = (float*)alloc(sizeof(float) * E_ * H_);
  float* LST   = (float*)alloc(sizeof(float) * E_ * 32);
  float* GI    = (float*)alloc(sizeof(float) * E_ * H_);
  unsigned short* Zb  = (unsigned short*)alloc(sizeof(short) * (size_t)T_ * H_);
  unsigned short* OWB = (unsigned short*)alloc(sizeof(short) * (size_t)V_ * H_);
  int* pre_done = (int*)alloc(sizeof(int) * (T_ + 64));  // prog_h tails the array
  int* prog_h   = pre_done + T_;

  hipMemsetAsync(pre_done, 0, sizeof(int) * (T_ + 64), stream);
  hipLaunchKernelGGL(k_prep, dim3(4096), dim3(256), 0, stream,
                     out_W, W_ih, W_hh, OWB, WT, WP);
  hipLaunchKernelGGL(k_cm, dim3(512), dim3(256), 0, stream,
                     Wdelta_W, Went_W, We_W, r_emb, Wr_W, Wlen_W, CMR);
  hipLaunchKernelGGL(k_init, dim3(256), dim3(256), 0, stream,
                     E0, Went_W, We_W, Wlen_W, GI, MST, LST, ENTS);
  hipLaunchKernelGGL(k_a, dim3(T_ / 8), dim3(1024), 0, stream,
                     tokens, emb, WT, b_ih, b_hh, A4);
  hipLaunchKernelGGL(k_pipe, dim3(2 + NPREB), dim3(512), 0, stream,
                     (const uint4*)WP, (const floatx4*)A4, Hws, CMR, PRE,
                     eids, GI, dist0, We_b, Wlen_b,
                     wdist_W, wdist_b, Wdelta_b, Went_b, Wr_b,
                     ENTS, MST, LST, Zb, out, prog_h, pre_done);
  hipLaunchKernelGGL(k_gemm, dim3(16, 393), dim3(256), 0, stream,
                     OWB, Zb, out_b, out);
}